// Round 8
// baseline (53.488 us; speedup 1.0000x reference)
//
#include <hip/hip_runtime.h>

#define NQ 12
#define NL 4
typedef __attribute__((ext_vector_type(2))) float f32x2;   // (re, im)

// Amp index i[11:0], wire w <-> bit 11-w. 256 threads t[7:0], 16 regs r[3:0].
// Mapping A: i = (t<<4)|r              -> r = wires 8..11
// Mapping B: i = t[7:4]<<8|r<<4|t[3:0] -> r = wires 4..7
// Mapping C: i = (r<<8)|t              -> r = wires 0..3
// Layer: D_phi (A) ; RY 8-11 (A) ; perm->B ; RY 4-7 (B) ; perm->C ;
//        RY 0-3 (C) ; D_omega (C) ; perm->A with ring-CNOTs folded into
//        read addressing (GF(2)-linear, verified R5/R6).
// Diagonals: thread-part = sincos of signed sum (+ per-layer offset), reg-part
// = 4 shared RZ factors applied to set-bit regs (replaces LDS tables).
// TWO batch elements per block; perms staggered through one 32 KB buffer.

__device__ __forceinline__ f32x2 cmul(f32x2 a, f32x2 b) {
    f32x2 r; r.x = a.x*b.x - a.y*b.y; r.y = a.x*b.y + a.y*b.x; return r;
}

// LDS swizzle on amp index: XOR higher bits into bank bits [3:1].
__device__ __forceinline__ int SW(int i) {
    return i ^ ((((i >> 4) ^ (i >> 8)) & 7) << 1);
}

template<int P>
__device__ __forceinline__ void ry16(f32x2 (&v)[16], float ct, float sn) {
#pragma unroll
    for (int r0 = 0; r0 < 16; ++r0) {
        if (!(r0 & (1 << P))) {
            const int r1 = r0 | (1 << P);
            const f32x2 a0 = v[r0], a1 = v[r1];
            v[r0] = ct*a0 - sn*a1;
            v[r1] = sn*a0 + ct*a1;
        }
    }
}

__device__ __forceinline__ void ry4grp(f32x2 (&v)[16], const f32x2* rc) {
    const f32x2 c0 = rc[0], c1 = rc[1], c2 = rc[2], c3 = rc[3];
    ry16<3>(v, c0.x, c0.y);
    ry16<2>(v, c1.x, c1.y);
    ry16<1>(v, c2.x, c2.y);
    ry16<0>(v, c3.x, c3.y);
}

// v[r] *= tc * f0^{bit3} * f1^{bit2} * f2^{bit1} * f3^{bit0}
__device__ __forceinline__ void diag_rz(f32x2 (&v)[16], f32x2 tc, const f32x2* fz) {
    const f32x2 f0 = fz[0], f1 = fz[1], f2 = fz[2], f3 = fz[3];
#pragma unroll
    for (int r = 0; r < 16; ++r) v[r] = cmul(v[r], tc);
#pragma unroll
    for (int r = 8; r < 16; ++r) v[r] = cmul(v[r], f0);
#pragma unroll
    for (int r = 0; r < 16; ++r) if (r & 4) v[r] = cmul(v[r], f1);
#pragma unroll
    for (int r = 0; r < 16; ++r) if (r & 2) v[r] = cmul(v[r], f2);
#pragma unroll
    for (int r = 0; r < 16; ++r) if (r & 1) v[r] = cmul(v[r], f3);
}

// Ring fold columns for dst reg bits (verified R5: S_rho = inverse ring map).
__device__ constexpr int foldG(int rho, int r) {
    int g = 0;
    if (rho == 1) {
        if (r & 1) g ^= 0xC01; if (r & 2) g ^= 0x003;
        if (r & 4) g ^= 0x006; if (r & 8) g ^= 0x00C;
    } else if (rho == 2) {
        if (r & 1) g ^= 0x501; if (r & 2) g ^= 0xA02;
        if (r & 4) g ^= 0x005; if (r & 8) g ^= 0x00A;
    } else {
        if (r & 1) g ^= 0x241; if (r & 2) g ^= 0x482;
        if (r & 4) g ^= 0x904; if (r & 8) g ^= 0x009;
    }
    return g;
}

template<int RHO>
__device__ __forceinline__ void readCA(f32x2 (&v)[16], const f32x2* buf, int t) {
    int F;   // thread-part columns (dst bits 4..11)
    if constexpr (RHO == 1) F = (t << 4) ^ ((t & 127) << 3) ^ ((t >> 7) << 10);
    else if constexpr (RHO == 2) F = (t << 4) ^ ((t & 255) << 2);
    else F = (t << 4) ^ ((t & 255) << 1);
#pragma unroll
    for (int r = 0; r < 16; ++r)
        v[r] = buf[SW(F ^ foldG(RHO, r))];
}

__device__ __forceinline__ void permA_write(const f32x2 (&v)[16], f32x2* buf, int t) {
    float4* b4 = (float4*)buf;
    const int base = t << 4;
#pragma unroll
    for (int r = 0; r < 16; r += 2) {
        const int a = SW(base | r);
        b4[a >> 1] = make_float4(v[r].x, v[r].y, v[r+1].x, v[r+1].y);
    }
}
__device__ __forceinline__ void permB_read(f32x2 (&v)[16], const f32x2* buf, int t) {
    const int hi = (t & 0xF0) << 4, lo = t & 15;
#pragma unroll
    for (int r = 0; r < 16; ++r) v[r] = buf[SW(hi | (r << 4) | lo)];
}
__device__ __forceinline__ void permB_write(const f32x2 (&v)[16], f32x2* buf, int t) {
    const int hi = (t & 0xF0) << 4, lo = t & 15;
#pragma unroll
    for (int r = 0; r < 16; ++r) buf[SW(hi | (r << 4) | lo)] = v[r];
}
__device__ __forceinline__ void permC_read(f32x2 (&v)[16], const f32x2* buf, int t) {
#pragma unroll
    for (int r = 0; r < 16; ++r) v[r] = buf[SW((r << 8) | t)];
}
__device__ __forceinline__ void permC_write(const f32x2 (&v)[16], f32x2* buf, int t) {
#pragma unroll
    for (int r = 0; r < 16; ++r) buf[SW((r << 8) | t)] = v[r];
}

__device__ __forceinline__ void embed(f32x2 (&v)[16], const float* __restrict__ xr, int t) {
    float cw[NQ], sw[NQ];
#pragma unroll
    for (int w = 0; w < NQ; ++w) __sincosf(0.5f * xr[w], &sw[w], &cw[w]);
    float lm = 1.f;
#pragma unroll
    for (int k = 0; k < 8; ++k) lm *= ((t >> k) & 1) ? sw[7-k] : cw[7-k];
    const int pt = __popc(t) & 3;
    float pre[4], pim[4];
#pragma unroll
    for (int q = 0; q < 4; ++q) {
        const int kk = (pt + q) & 3;      // (-i)^(pt+q)
        pre[q] = (kk == 0) ? 1.f : ((kk == 2) ? -1.f : 0.f);
        pim[q] = (kk == 1) ? -1.f : ((kk == 3) ? 1.f : 0.f);
    }
#pragma unroll
    for (int r = 0; r < 16; ++r) {
        float m = lm;
        m *= (r & 1) ? sw[11] : cw[11];
        m *= (r & 2) ? sw[10] : cw[10];
        m *= (r & 4) ? sw[9]  : cw[9];
        m *= (r & 8) ? sw[8]  : cw[8];
        const int pc = __popc(r) & 3;
        v[r].x = m * pre[pc];
        v[r].y = m * pim[pc];
    }
}

// <Z_w> partials, mapping C, ring-3 (rho=4) folded into parity masks.
__device__ __forceinline__ void meas(const f32x2 (&v)[16], float (&ev)[NQ], int t) {
    float S0 = 0.f, S8 = 0.f, S4 = 0.f, S2 = 0.f, S1 = 0.f;
#pragma unroll
    for (int r = 0; r < 16; ++r) {
        const float p = v[r].x*v[r].x + v[r].y*v[r].y;
        S0 += p;
        S8 += (r & 8) ? -p : p;
        S4 += (r & 4) ? -p : p;
        S2 += (r & 2) ? -p : p;
        S1 += (r & 1) ? -p : p;
    }
    const float g88 = (__popc(t & 0x88) & 1) ? -1.f : 1.f;
    const float g44 = (__popc(t & 0x44) & 1) ? -1.f : 1.f;
    const float g22 = (__popc(t & 0x22) & 1) ? -1.f : 1.f;
    const float g11 = (__popc(t & 0x11) & 1) ? -1.f : 1.f;
    const float g80 = (t & 0x80) ? -1.f : 1.f;
    const float g40 = (t & 0x40) ? -1.f : 1.f;
    const float g20 = (t & 0x20) ? -1.f : 1.f;
    const float g10 = (t & 0x10) ? -1.f : 1.f;
    ev[0] = g88 * S0;  ev[1] = g44 * S0;  ev[2]  = g22 * S0;  ev[3]  = g11 * S0;
    ev[4] = g80 * S8;  ev[5] = g40 * S4;  ev[6]  = g20 * S2;  ev[7]  = g10 * S1;
    ev[8] = g88 * S8;  ev[9] = g44 * S4;  ev[10] = g22 * S2;  ev[11] = g11 * S1;
}

__global__ __launch_bounds__(256) void vqc_kernel(
    const float* __restrict__ x,      // (B, 12)
    const float* __restrict__ wts,    // (4, 12, 3)
    float* __restrict__ out)          // (B, 12)
{
    __shared__ alignas(16) f32x2 buf[4096];      // 32 KB exchange
    __shared__ alignas(16) f32x2 rcs[NL * NQ];   // (cos,sin)(theta/2) per wire
    __shared__ alignas(16) f32x2 rzP[NL][4];     // e^{i phi_{l,8+j}}
    __shared__ alignas(16) f32x2 rzW[3][4];      // e^{i omega_{l,j}}
    __shared__ float offs[8];                    // offP[0..3], offW[0..2]@4..6
    __shared__ float red[2][4][NQ];

    const int t  = threadIdx.x;
    const int b0 = blockIdx.x * 2, b1 = b0 + 1;

    // ---- static tables (batch-independent) ----
    if (t < NL * NQ) {
        float s, c; __sincosf(0.5f * wts[t*3 + 1], &s, &c);
        f32x2 tv = {c, s}; rcs[t] = tv;
    } else if (t < 64) {
        const int u = t - 48, l = u >> 2, j = u & 3;
        float s, c; __sincosf(wts[(l*NQ + 8 + j)*3 + 0], &s, &c);
        f32x2 tv = {c, s}; rzP[l][j] = tv;
    } else if (t < 76) {
        const int u = t - 64, l = u >> 2, j = u & 3;
        float s, c; __sincosf(wts[(l*NQ + j)*3 + 2], &s, &c);
        f32x2 tv = {c, s}; rzW[l][j] = tv;
    } else if (t < 80) {
        const int l = t - 76;
        float s = 0.f;
#pragma unroll
        for (int j = 0; j < 4; ++j) s += wts[(l*NQ + 8 + j)*3 + 0];
        offs[l] = -0.5f * s;
    } else if (t < 83) {
        const int l = t - 80;
        float s = 0.f;
#pragma unroll
        for (int j = 0; j < 4; ++j) s += wts[(l*NQ + j)*3 + 2];
        offs[4 + l] = -0.5f * s;
    }

    // ---- AngleEmbedding closed form, both elements (mapping A) ----
    f32x2 v0[16], v1[16];
    embed(v0, x + b0*NQ, t);
    embed(v1, x + b1*NQ, t);
    __syncthreads();

    // ---- 4 layers ----
#pragma unroll 1
    for (int l = 0; l < NL; ++l) {
        // D_phi thread part: wires 0..7, t bit k <-> wire 7-k (scalar loads)
        float aP = offs[l];
#pragma unroll
        for (int k = 0; k < 8; ++k)
            aP += (((t >> k) & 1) ? 0.5f : -0.5f) * wts[(l*NQ + (7-k))*3 + 0];
        float sp, cp; __sincosf(aP, &sp, &cp);
        f32x2 tcP = {cp, sp};
        diag_rz(v0, tcP, rzP[l]);
        diag_rz(v1, tcP, rzP[l]);
        ry4grp(v0, &rcs[l*NQ + 8]);        // RY wires 8..11 (A)
        ry4grp(v1, &rcs[l*NQ + 8]);

        // ---- perm A -> B, staggered ----
        __syncthreads(); permA_write(v0, buf, t);
        __syncthreads(); permB_read(v0, buf, t);
        __syncthreads(); permA_write(v1, buf, t);
        __syncthreads(); permB_read(v1, buf, t);
        ry4grp(v0, &rcs[l*NQ + 4]);        // RY wires 4..7 (B)
        ry4grp(v1, &rcs[l*NQ + 4]);

        // ---- perm B -> C, staggered ----
        __syncthreads(); permB_write(v0, buf, t);
        __syncthreads(); permC_read(v0, buf, t);
        __syncthreads(); permB_write(v1, buf, t);
        __syncthreads(); permC_read(v1, buf, t);
        ry4grp(v0, &rcs[l*NQ + 0]);        // RY wires 0..3 (C)
        ry4grp(v1, &rcs[l*NQ + 0]);

        if (l == NL - 1) break;            // trailing phases + ring-3 in masks

        // D_omega thread part: wires 4..11, t bit k <-> wire 11-k
        float aW = offs[4 + l];
#pragma unroll
        for (int k = 0; k < 8; ++k)
            aW += (((t >> k) & 1) ? 0.5f : -0.5f) * wts[(l*NQ + (11-k))*3 + 2];
        float so, co; __sincosf(aW, &so, &co);
        f32x2 tcW = {co, so};
        diag_rz(v0, tcW, rzW[l]);
        diag_rz(v1, tcW, rzW[l]);

        // ---- perm C -> A with ring fold, staggered ----
        __syncthreads(); permC_write(v0, buf, t);
        __syncthreads();
        if (l == 0)      readCA<1>(v0, buf, t);
        else if (l == 1) readCA<2>(v0, buf, t);
        else             readCA<3>(v0, buf, t);
        __syncthreads(); permC_write(v1, buf, t);
        __syncthreads();
        if (l == 0)      readCA<1>(v1, buf, t);
        else if (l == 1) readCA<2>(v1, buf, t);
        else             readCA<3>(v1, buf, t);
    }

    // ---- measurement, both elements ----
    float ev0[NQ], ev1[NQ];
    meas(v0, ev0, t);
    meas(v1, ev1, t);
#pragma unroll
    for (int w = 0; w < NQ; ++w) {
#pragma unroll
        for (int off = 32; off; off >>= 1) {
            ev0[w] += __shfl_xor(ev0[w], off, 64);
            ev1[w] += __shfl_xor(ev1[w], off, 64);
        }
    }
    if ((t & 63) == 0) {
#pragma unroll
        for (int w = 0; w < NQ; ++w) {
            red[0][t >> 6][w] = ev0[w];
            red[1][t >> 6][w] = ev1[w];
        }
    }
    __syncthreads();
    if (t < NQ)
        out[b0*NQ + t] = red[0][0][t] + red[0][1][t] + red[0][2][t] + red[0][3][t];
    else if (t >= 64 && t < 64 + NQ) {
        const int w = t - 64;
        out[b1*NQ + w] = red[1][0][w] + red[1][1][w] + red[1][2][w] + red[1][3][w];
    }
}

extern "C" void kernel_launch(void* const* d_in, const int* in_sizes, int n_in,
                              void* d_out, int out_size, void* d_ws, size_t ws_size,
                              hipStream_t stream) {
    const float* x   = (const float*)d_in[0];
    const float* wts = (const float*)d_in[1];
    float* out = (float*)d_out;
    const int nb2 = (in_sizes[0] / NQ) / 2;
    vqc_kernel<<<dim3(nb2), dim3(256), 0, stream>>>(x, wts, out);
}